// Round 9
// baseline (9097.503 us; speedup 1.0000x reference)
//
#include <hip/hip_runtime.h>
#include <hip/hip_bf16.h>

#define N_NODES 262144
#define N_EDGES 1048576
#define NC      30
#define ED      13
#define H       256
#define GH      512
#define OUT_C   256
#define NLAYERS 4
#define NGRAPHS 8192

typedef __hip_bfloat16 bf16;

__device__ __forceinline__ float hw2f(unsigned short h) {
    return __uint_as_float(((unsigned int)h) << 16);
}
__device__ __forceinline__ float ldf(const void* p, size_t i, bool isbf) {
    return isbf ? hw2f(((const unsigned short*)p)[i]) : ((const float*)p)[i];
}
__device__ __forceinline__ int ldi(const void* p, size_t j, bool is64) {
    return ((const int*)p)[is64 ? 2 * j : j];   // little-endian lo word
}
__device__ __forceinline__ unsigned short bfbits(float f) {
    bf16 b = __float2bfloat16(f);
    return *(unsigned short*)&b;
}
// float width sniff: even halfwords. bf16 data -> plausible exponents
// (~32/32 hits). fp32 data -> low mantissa halves, uniform junk (~6/32).
__device__ __forceinline__ bool sniff_bf16(const void* xv) {
    const unsigned short* q = (const unsigned short*)xv;
    int c = 0;
    for (int i = 0; i < 32; ++i) {
        unsigned short h = q[2 * i];
        int e = (h >> 7) & 0xFF;
        c += (h == 0 || (e >= 97 && e <= 141)) ? 1 : 0;
    }
    return c >= 20;
}
// int width sniff: odd 32-bit words all zero <=> int64 (values < 2^31).
__device__ __forceinline__ bool sniff_i64(const void* pv, size_t baseWord) {
    const unsigned int* q = (const unsigned int*)pv;
    int z = 0;
    for (int i = 0; i < 32; ++i) z += (q[baseWord + 2 * i + 1] == 0) ? 1 : 0;
    return z >= 20;
}
// packed bf16x2 add via 32-bit CAS (avg in-degree 4: low contention)
__device__ __forceinline__ void cas_add_bf16x2(unsigned int* addr, float v0, float v1) {
    unsigned int old = __hip_atomic_load(addr, __ATOMIC_RELAXED,
                                         __HIP_MEMORY_SCOPE_AGENT);
    unsigned int assumed;
    do {
        assumed = old;
        float a0 = __uint_as_float((assumed & 0xFFFFu) << 16);
        float a1 = __uint_as_float(assumed & 0xFFFF0000u);
        unsigned int nv = (unsigned int)bfbits(a0 + v0) |
                          ((unsigned int)bfbits(a1 + v1) << 16);
        old = atomicCAS(addr, assumed, nv);
    } while (old != assumed);
}

// ---------------------------------------------------------------- fills
__global__ __launch_bounds__(256) void fill_f4(float4* p, int n4, float val) {
    int i = blockIdx.x * 256 + threadIdx.x;
    int stride = gridDim.x * 256;
    float4 z = make_float4(val, val, val, val);
    for (; i < n4; i += stride) p[i] = z;
}

// ------------------------------------------------- hid = x @ W_nh + b_nh
__global__ __launch_bounds__(256) void node_proj(
        const void* __restrict__ x, const void* __restrict__ W,
        const void* __restrict__ b, bf16* __restrict__ hid) {
    const bool isbf = sniff_bf16(x);
    __shared__ float xs[16 * NC];
    const int m0 = blockIdx.x * 16;
    for (int i = threadIdx.x; i < 16 * NC; i += 256)
        xs[i] = ldf(x, (size_t)m0 * NC + i, isbf);
    __syncthreads();
    const int col = threadIdx.x;
    float w[NC];
#pragma unroll
    for (int k = 0; k < NC; ++k) w[k] = ldf(W, (size_t)k * H + col, isbf);
    const float bias = ldf(b, col, isbf);
#pragma unroll 4
    for (int r = 0; r < 16; ++r) {
        float acc = bias;
#pragma unroll
        for (int k = 0; k < NC; ++k) acc += xs[r * NC + k] * w[k];
        hid[(size_t)(m0 + r) * H + col] = __float2bfloat16(acc);
    }
}

// ---- per-edge, all edges one pass (hid = layer-l values everywhere):
// e = eattr@We[l]+be[l] ; msg = relu(hid[src]+e) ; agg[dst] += msg
// AGGB=0: fp32 agg, plain atomicAdd.  AGGB=1: bf16 agg, packed CAS add.
template <int AGGB>
__global__ __launch_bounds__(256) void edge_full(
        const void* __restrict__ eattr, const void* __restrict__ eidx,
        const void* __restrict__ We, size_t weOff,
        const void* __restrict__ be, size_t beOff,
        const bf16* __restrict__ hid,
        float* __restrict__ aggf, unsigned int* __restrict__ aggb) {
    const bool isbf = sniff_bf16(eattr);
    const bool is64 = sniff_i64(eidx, 0);
    __shared__ float Ws[ED * H];
    __shared__ float bs[H];
    for (int i = threadIdx.x; i < ED * H; i += 256)
        Ws[i] = ldf(We, weOff + i, isbf);
    for (int i = threadIdx.x; i < H; i += 256)
        bs[i] = ldf(be, beOff + i, isbf);
    __syncthreads();
    const int wave = threadIdx.x >> 6;
    const int lane = threadIdx.x & 63;
    const int e0 = blockIdx.x * 64;
    for (int it = 0; it < 16; ++it) {
        const int e = e0 + it * 4 + wave;
        int src = ldi(eidx, e, is64);
        int dst = ldi(eidx, (size_t)N_EDGES + e, is64);
        if ((unsigned)src >= (unsigned)N_NODES) src = 0;   // safety clamp
        if ((unsigned)dst >= (unsigned)N_NODES) dst = 0;
        float af[ED];
        for (int k = 0; k < ED; ++k)
            af[k] = ldf(eattr, (size_t)e * ED + k, isbf);
        const unsigned short* hrow = (const unsigned short*)hid + (size_t)src * H;
        if (AGGB == 0) {
            float* arow = aggf + (size_t)dst * H;
#pragma unroll
            for (int j = 0; j < 4; ++j) {
                const int col = lane + 64 * j;
                float v = bs[col];
#pragma unroll
                for (int k = 0; k < ED; ++k) v += af[k] * Ws[k * H + col];
                v += hw2f(hrow[col]);
                atomicAdd(arow + col, fmaxf(v, 0.f));
            }
        } else {
            unsigned int* arow = aggb + (size_t)dst * (H / 2);
#pragma unroll
            for (int j = 0; j < 2; ++j) {
                const int c0 = 2 * lane + 128 * j;
                float v0 = bs[c0], v1 = bs[c0 + 1];
#pragma unroll
                for (int k = 0; k < ED; ++k) {
                    v0 += af[k] * Ws[k * H + c0];
                    v1 += af[k] * Ws[k * H + c0 + 1];
                }
                unsigned int h2 = *(const unsigned int*)(hrow + c0);
                v0 += __uint_as_float((h2 & 0xFFFFu) << 16);
                v1 += __uint_as_float(h2 & 0xFFFF0000u);
                cas_add_bf16x2(arow + lane + 64 * j, fmaxf(v0, 0.f), fmaxf(v1, 0.f));
            }
        }
    }
}

// ------------------------------------------------------------- K=256 GEMM
// acc = (widen(A) [+A2f | +widen(A2b)]) @ B;  BM=32 BN=256 BK=32, 4x8.
// Cross-validated vs clean-room gemm_col in R8 (identical outputs).
// MODE 0: Cb = bf16(act(acc+bias)); in-place over A safe (block owns rows).
// MODE 1: fp32 atomicAdd into Cf[batch[row+batOff]*OUT_C+col]  (fp32 d_out).
template <int MODE>
__global__ __launch_bounds__(256) void gemm256(
        const bf16* __restrict__ A, const float* __restrict__ A2f,
        const bf16* __restrict__ A2b,
        const void* __restrict__ B, size_t bOff, int ldb,
        const void* __restrict__ bias, size_t biasOff,
        bf16* __restrict__ Cb, float* __restrict__ Cf,
        const void* __restrict__ batch, size_t batOff,
        int doRelu, int useBias) {
    const bool isbf = sniff_bf16(B);
    __shared__ float As[32][36];
    __shared__ float Bs[32 * 256];
    const int tid = threadIdx.x;
    const int tx  = tid & 31;
    const int ty4 = (tid >> 5) * 4;
    const int m0  = blockIdx.x * 32;
    const int a_lk = tid & 7;
    const int a_lm = tid >> 3;
    const int b_n4 = tid & 63;
    const int b_kk = tid >> 6;

    float acc[4][8];
#pragma unroll
    for (int i = 0; i < 4; ++i)
#pragma unroll
        for (int j = 0; j < 8; ++j) acc[i][j] = 0.f;

    for (int kt = 0; kt < 8; ++kt) {
        const int k0 = kt * 32;
        {
            const size_t off = (size_t)(m0 + a_lm) * H + k0 + a_lk * 4;
            ushort4 u = *(const ushort4*)((const unsigned short*)A + off);
            float4 av;
            av.x = hw2f(u.x); av.y = hw2f(u.y); av.z = hw2f(u.z); av.w = hw2f(u.w);
            if (A2f) {
                const float4 a2 = *(const float4*)(A2f + off);
                av.x += a2.x; av.y += a2.y; av.z += a2.z; av.w += a2.w;
            } else if (A2b) {
                ushort4 u2 = *(const ushort4*)((const unsigned short*)A2b + off);
                av.x += hw2f(u2.x); av.y += hw2f(u2.y);
                av.z += hw2f(u2.z); av.w += hw2f(u2.w);
            }
            As[a_lk * 4 + 0][a_lm] = av.x;
            As[a_lk * 4 + 1][a_lm] = av.y;
            As[a_lk * 4 + 2][a_lm] = av.z;
            As[a_lk * 4 + 3][a_lm] = av.w;
        }
#pragma unroll
        for (int p = 0; p < 8; ++p) {
            const int k = b_kk + p * 4;
            const size_t off = bOff + (size_t)(k0 + k) * ldb + b_n4 * 4;
            float4 f;
            if (isbf) {
                ushort4 u = *(const ushort4*)((const unsigned short*)B + off);
                f.x = hw2f(u.x); f.y = hw2f(u.y); f.z = hw2f(u.z); f.w = hw2f(u.w);
            } else {
                f = *(const float4*)((const float*)B + off);
            }
            *(float4*)&Bs[k * 256 + b_n4 * 4] = f;
        }
        __syncthreads();
#pragma unroll
        for (int k = 0; k < 32; ++k) {
            const float4 av = *(const float4*)&As[k][ty4];
            float bv[8];
#pragma unroll
            for (int j = 0; j < 8; ++j) bv[j] = Bs[k * 256 + tx + 32 * j];
#pragma unroll
            for (int j = 0; j < 8; ++j) {
                acc[0][j] += av.x * bv[j];
                acc[1][j] += av.y * bv[j];
                acc[2][j] += av.z * bv[j];
                acc[3][j] += av.w * bv[j];
            }
        }
        __syncthreads();
    }

    if (MODE == 0) {
#pragma unroll
        for (int j = 0; j < 8; ++j) {
            const int col = tx + 32 * j;
            const float bc = ldf(bias, biasOff + col, isbf);
#pragma unroll
            for (int i = 0; i < 4; ++i) {
                float v = acc[i][j] + bc;
                if (doRelu) v = fmaxf(v, 0.f);
                Cb[(size_t)(m0 + ty4 + i) * H + col] = __float2bfloat16(v);
            }
        }
    } else {
        const bool is64 = sniff_i64(batch, N_NODES / 2);
        int bg[4];
#pragma unroll
        for (int i = 0; i < 4; ++i) {
            int g = ldi(batch, batOff + m0 + ty4 + i, is64);
            bg[i] = ((unsigned)g < (unsigned)NGRAPHS) ? g : 0;   // safety clamp
        }
#pragma unroll
        for (int j = 0; j < 8; ++j) {
            const int col = tx + 32 * j;
            const float bc = useBias ? ldf(bias, biasOff + col, isbf) : 0.f;
            float run = 0.f;
#pragma unroll
            for (int i = 0; i < 4; ++i) {
                run += acc[i][j] + bc;
                if (i == 3 || bg[i + 1] != bg[i]) {
                    atomicAdd(&Cf[(size_t)bg[i] * OUT_C + col], run);
                    run = 0.f;
                }
            }
        }
    }
}

// ---------------------------------------------------------------- launcher
extern "C" void kernel_launch(void* const* d_in, const int* in_sizes, int n_in,
                              void* d_out, int out_size, void* d_ws, size_t ws_size,
                              hipStream_t stream) {
    // size-based input mapping (proven == dict order in R6/R7)
    const void *x = nullptr, *eattr = nullptr, *eidx = nullptr, *batch = nullptr;
    const void *W_nh = nullptr, *W1 = nullptr, *We = nullptr, *be = nullptr;
    const void *Wl1 = nullptr, *Wl2 = nullptr, *bl1 = nullptr;
    const void *z256[3] = {nullptr, nullptr, nullptr};
    int nz = 0;
    for (int i = 0; i < n_in; ++i) {
        switch (in_sizes[i]) {
            case N_NODES * NC:     x     = d_in[i]; break;
            case N_EDGES * ED:     eattr = d_in[i]; break;
            case 2 * N_EDGES:      eidx  = d_in[i]; break;
            case N_NODES:          batch = d_in[i]; break;
            case NC * H:           W_nh  = d_in[i]; break;
            case H * H:            W1    = d_in[i]; break;
            case NLAYERS * ED * H: We    = d_in[i]; break;
            case NLAYERS * H:      be    = d_in[i]; break;
            case H * GH:           if (!Wl1) Wl1 = d_in[i]; else Wl2 = d_in[i]; break;
            case GH:               bl1   = d_in[i]; break;
            case H:                if (nz < 3) z256[nz++] = d_in[i]; break;
            default: break;
        }
    }
    const void* b_nh = z256[0];
    const void* b1   = (nz > 1) ? z256[1] : z256[0];
    const void* bl2  = (nz > 2) ? z256[2] : z256[0];
    float* out = (float*)d_out;   // reference output dtype is FLOAT32

    if (!x || !eattr || !eidx || !batch || !W_nh || !W1 || !We || !be ||
        !Wl1 || !Wl2 || !bl1 || !b_nh) {
        fill_f4<<<1024, 256, 0, stream>>>((float4*)out, NGRAPHS * OUT_C / 4, 2.0e6f);
        return;  // sentinel: size-mapping failed
    }

    const size_t NH = (size_t)N_NODES * H;
    const size_t MB = 1024 * 1024;
    const size_t needA = NH * 4 + NH * 2;   // fp32 agg + bf16 hid = 384 MiB
    const size_t needB = NH * 2 + NH * 2;   // bf16 agg + bf16 hid = 256 MiB

    float* aggf = nullptr;
    unsigned int* aggb = nullptr;
    bf16* hid;
    if (ws_size >= needA) {
        aggf = (float*)d_ws;
        hid  = (bf16*)((char*)d_ws + NH * 4);
    } else if (ws_size >= needB) {
        aggb = (unsigned int*)d_ws;
        hid  = (bf16*)((char*)d_ws + NH * 2);
    } else {
        fill_f4<<<1024, 256, 0, stream>>>((float4*)out, NGRAPHS * OUT_C / 4, 1.0e6f);
        return;  // sentinel: ws too small
    }
    bf16* t0 = (bf16*)((char*)d_ws + 16 * MB);  // 32 MiB readout temp, aliases dead agg

    node_proj<<<N_NODES / 16, 256, 0, stream>>>(x, W_nh, b_nh, hid);

    for (int l = 0; l < NLAYERS; ++l) {
        if (aggf) {
            fill_f4<<<8192, 256, 0, stream>>>((float4*)aggf, (int)(NH / 4), 0.f);
            edge_full<0><<<N_EDGES / 64, 256, 0, stream>>>(
                eattr, eidx, We, (size_t)l * ED * H, be, (size_t)l * H,
                hid, aggf, nullptr);
        } else {
            fill_f4<<<8192, 256, 0, stream>>>((float4*)aggb, (int)(NH * 2 / 16), 0.f);
            edge_full<1><<<N_EDGES / 64, 256, 0, stream>>>(
                eattr, eidx, We, (size_t)l * ED * H, be, (size_t)l * H,
                hid, nullptr, aggb);
        }
        // hid = relu((hid + agg) @ W1 + b1), in-place (block owns its rows)
        gemm256<0><<<N_NODES / 32, 256, 0, stream>>>(
            hid, aggf, (const bf16*)aggb, W1, 0, H, b1, 0,
            hid, nullptr, nullptr, 0, 1, 1);
    }

    // readout: out[g] += (relu(hid@Wl1+bl1) @ Wl2 + bl2) pooled over batch,
    // fp32 atomics DIRECTLY into d_out; GH in 2 K-chunks, nodes in 4 chunks.
    fill_f4<<<2048, 256, 0, stream>>>((float4*)out, NGRAPHS * OUT_C / 4, 0.f);
    for (int c = 0; c < 2; ++c) {
        for (int m = 0; m < 4; ++m) {
            const size_t mbase = (size_t)m * 65536;
            gemm256<0><<<65536 / 32, 256, 0, stream>>>(
                hid + mbase * H, nullptr, nullptr,
                Wl1, (size_t)c * 256, GH, bl1, (size_t)c * 256,
                t0, nullptr, nullptr, 0, 1, 1);
            gemm256<1><<<65536 / 32, 256, 0, stream>>>(
                t0, nullptr, nullptr,
                Wl2, (size_t)c * 256 * OUT_C, OUT_C, bl2, 0,
                nullptr, out, batch, mbase, 0, c == 0);
        }
    }
}